// Round 9
// baseline (5666.961 us; speedup 1.0000x reference)
//
#include <hip/hip_runtime.h>
#include <math.h>

#define TT 128
#define ZD 2048
#define IFC 471
#define EPSF 1e-6f
#define MST 68      // M LDS row stride
#define LST 132     // link LDS row stride
#define NBLK 160
#define UHT 24640   // per-t stride of Uh: 32*768 + 64 guard floats
#define VHT 15424   // per-t stride of Vh: 32*480 + 64 guard floats
#define USS 516     // staged activation LDS row stride
#define WSS 772     // z weight slice LDS row stride
#define WIS 516     // iface weight slice LDS row stride

// dataflow flag arrays (unsigned), disjoint cache-line sets
#define FH_OFF 0     // [128] col h arrivals
#define FV_OFF 128   // [128] col v arrivals
#define FR_OFF 256   // [32]  state reads arrivals
#define NFLAGS 512

#define D4(a,b) ((a).x*(b).x + (a).y*(b).y + (a).z*(b).z + (a).w*(b).w)

__device__ __forceinline__ float sig_(float x){ return 1.f/(1.f+expf(-x)); }
__device__ __forceinline__ float sp_(float x){ return fmaxf(x,0.f)+log1pf(expf(-fabsf(x))); }

// -------- agent-scope (write-through, cache-bypassing) publishes --------
__device__ __forceinline__ void st1(float* p, float v){
  unsigned u; __builtin_memcpy(&u,&v,4);
  __hip_atomic_store((unsigned*)p, u, __ATOMIC_RELAXED, __HIP_MEMORY_SCOPE_AGENT);
}
__device__ __forceinline__ void st2(float* p, float2 v){
  unsigned long long u; __builtin_memcpy(&u,&v,8);
  __hip_atomic_store((unsigned long long*)p, u, __ATOMIC_RELAXED, __HIP_MEMORY_SCOPE_AGENT);
}

// -------- dataflow sync ------------------------------------------------
// arrive: __syncthreads() drains vmcnt(0) (payload store acks) before the
// flag RMW; the RMW commits at the coherent point on arrival.
__device__ __forceinline__ void arrive(unsigned* f){
  __syncthreads();
  if (threadIdx.x == 0)
    __hip_atomic_fetch_add(f, 1u, __ATOMIC_RELAXED, __HIP_MEMORY_SCOPE_AGENT);
}
// wait_ge: wave 0 polls n flags. ROUND-9 CHANGE (single variable): steady-
// state poll interval lengthened to s_sleep(64) (~1.7us). Round-8 theory:
// 160 blocks x 64-lane uncached polls every ~0.3us saturate the ~10 flag
// cache lines at the coherent point; the producer's flag RMW and payload
// stores queue BEHIND the poll storm => the measured ~10us/hop. Lower poll
// rate => shorter queues => faster publish visibility, at the cost of
// <=1.7us detection overshoot.
__device__ __forceinline__ void wait_ge(const unsigned* f, int n, unsigned gen){
  if (threadIdx.x < 64){
    for (int i = threadIdx.x; i < n; i += 64){
      if (__hip_atomic_load(&f[i], __ATOMIC_RELAXED, __HIP_MEMORY_SCOPE_AGENT) >= gen) continue;
      bool done = false;
      for (int q = 0; q < 4; ++q){          // quick polls (~0.1us apart)
        __builtin_amdgcn_s_sleep(4);
        if (__hip_atomic_load(&f[i], __ATOMIC_RELAXED, __HIP_MEMORY_SCOPE_AGENT) >= gen){ done = true; break; }
      }
      while (!done){                        // low-rate steady state (~1.7us)
        __builtin_amdgcn_s_sleep(64);
        if (__hip_atomic_load(&f[i], __ATOMIC_RELAXED, __HIP_MEMORY_SCOPE_AGENT) >= gen) done = true;
      }
    }
  }
  __syncthreads();
}

// ---------------- GEMM #1: C[M,N] = A[M,K] @ B[K,N] + bias[N]
__global__ __launch_bounds__(256) void gemm_bias(
    const float* __restrict__ A, const float* __restrict__ B,
    const float* __restrict__ bias, float* __restrict__ C,
    int Nc, int K)
{
  __shared__ float As[16][68];
  __shared__ float Bs[16][68];
  const int tid = threadIdx.x;
  const int bx = blockIdx.x, by = blockIdx.y;
  const int tx = tid & 15, ty = tid >> 4;
  const int am = tid >> 2, ak = (tid & 3) * 4;
  const int bk = tid >> 4, bn = (tid & 15) * 4;
  float acc[4][4] = {};
  const float* Ap = A + (size_t)(by*64+am)*K + ak;
  const float* Bp = B + (size_t)bk*Nc + bx*64 + bn;
  for (int k0 = 0; k0 < K; k0 += 16) {
    float4 av = *(const float4*)Ap; Ap += 16;
    float4 bv = *(const float4*)Bp; Bp += (size_t)16*Nc;
    As[ak+0][am]=av.x; As[ak+1][am]=av.y; As[ak+2][am]=av.z; As[ak+3][am]=av.w;
    *(float4*)&Bs[bk][bn] = bv;
    __syncthreads();
#pragma unroll
    for (int kk = 0; kk < 16; ++kk) {
      float4 a4 = *(const float4*)&As[kk][ty*4];
      float4 b4 = *(const float4*)&Bs[kk][tx*4];
      acc[0][0]+=a4.x*b4.x; acc[0][1]+=a4.x*b4.y; acc[0][2]+=a4.x*b4.z; acc[0][3]+=a4.x*b4.w;
      acc[1][0]+=a4.y*b4.x; acc[1][1]+=a4.y*b4.y; acc[1][2]+=a4.y*b4.z; acc[1][3]+=a4.y*b4.w;
      acc[2][0]+=a4.z*b4.x; acc[2][1]+=a4.z*b4.y; acc[2][2]+=a4.z*b4.z; acc[2][3]+=a4.z*b4.w;
      acc[3][0]+=a4.w*b4.x; acc[3][1]+=a4.w*b4.y; acc[3][2]+=a4.w*b4.z; acc[3][3]+=a4.w*b4.w;
    }
    __syncthreads();
  }
  float4 bb = *(const float4*)(bias + bx*64 + tx*4);
#pragma unroll
  for (int i = 0; i < 4; ++i) {
    float4 o;
    o.x = acc[i][0]+bb.x; o.y = acc[i][1]+bb.y; o.z = acc[i][2]+bb.z; o.w = acc[i][3]+bb.w;
    *(float4*)(C + (size_t)(by*64+ty*4+i)*Nc + bx*64 + tx*4) = o;
  }
}

// ---------------- GEMM #2 (output): A rows live in Uh[t][e] layout.
__global__ __launch_bounds__(256) void gemm_out(
    const float* __restrict__ A, const float* __restrict__ B,
    const float* __restrict__ bias, float* __restrict__ C)
{
  __shared__ float As[16][68];
  __shared__ float Bs[16][68];
  const int tid = threadIdx.x;
  const int bx = blockIdx.x, by = blockIdx.y;
  const int tx = tid & 15, ty = tid >> 4;
  const int am = tid >> 2, ak = (tid & 3) * 4;
  const int bk = tid >> 4, bn = (tid & 15) * 4;
  float acc[4][4] = {};
  const int arow = by*64 + am;
  const float* Ap = A + (size_t)(arow >> 5)*UHT + (size_t)(arow & 31)*768 + ak;
  const float* Bp = B + (size_t)bk*512 + bx*64 + bn;
  for (int k0 = 0; k0 < 768; k0 += 16) {
    float4 av = *(const float4*)Ap; Ap += 16;
    float4 bv = *(const float4*)Bp; Bp += (size_t)16*512;
    As[ak+0][am]=av.x; As[ak+1][am]=av.y; As[ak+2][am]=av.z; As[ak+3][am]=av.w;
    *(float4*)&Bs[bk][bn] = bv;
    __syncthreads();
#pragma unroll
    for (int kk = 0; kk < 16; ++kk) {
      float4 a4 = *(const float4*)&As[kk][ty*4];
      float4 b4 = *(const float4*)&Bs[kk][tx*4];
      acc[0][0]+=a4.x*b4.x; acc[0][1]+=a4.x*b4.y; acc[0][2]+=a4.x*b4.z; acc[0][3]+=a4.x*b4.w;
      acc[1][0]+=a4.y*b4.x; acc[1][1]+=a4.y*b4.y; acc[1][2]+=a4.y*b4.z; acc[1][3]+=a4.y*b4.w;
      acc[2][0]+=a4.z*b4.x; acc[2][1]+=a4.z*b4.y; acc[2][2]+=a4.z*b4.z; acc[2][3]+=a4.z*b4.w;
      acc[3][0]+=a4.w*b4.x; acc[3][1]+=a4.w*b4.y; acc[3][2]+=a4.w*b4.z; acc[3][3]+=a4.w*b4.w;
    }
    __syncthreads();
  }
  float4 bb = *(const float4*)(bias + bx*64 + tx*4);
#pragma unroll
  for (int i = 0; i < 4; ++i) {
    int row = by*64 + ty*4 + i;
    int crow = (row & 31)*128 + (row >> 5);   // (e,t) -> e*128+t
    float4 o;
    o.x = acc[i][0]+bb.x; o.y = acc[i][1]+bb.y; o.z = acc[i][2]+bb.z; o.w = acc[i][3]+bb.w;
    *(float4*)(C + (size_t)crow*512 + bx*64 + tx*4) = o;
  }
}

// ---------------- state-block LDS layout (floats)
#define SL_L    0
#define SL_M    16896
#define SL_V    25600
#define SL_WR   26080
#define SL_FW   26592
#define SL_BW   27104
#define SL_CR   27616
#define SL_USG  28128
#define SL_PRC  28256
#define SL_WW   28384
#define SL_SU   28512
#define SL_CPX  28640
#define SL_MN   28768
#define SL_SW   28896
#define SL_CW   29024
#define SL_RNK  29152
#define SL_MSC  29280
#define SL_ER   29344
#define SL_WV   29408
#define SL_TOT  29472

// ---------------- col-block LDS layout (floats)
#define CL_WS  0                      // Ws [16][772] = 12352
#define CL_WI  12352                  // Wi [4][516]  = 2064
#define CL_US  14416                  // us [32][516] = 16512
#define CL_ZH  30928                  // zh [512]
#define CL_CS  31440                  // c  [128]
#define CL_HL  31568                  // h  [128]
#define CL_TOT 31696                  // 126784 bytes

__device__ __forceinline__ void zgemm(const float* Ws, const float* us, int wofs,
                                      int giters, float acc[4][4]) {
  const int tid = threadIdx.x;
  const int tile = tid >> 5, s = tid & 31;
  const int e0 = (tile >> 2)*4, jj = (tile & 3)*4;
  for (int g = 0; g < giters; ++g) {
    int kk = g*128 + s*4;
    float4 u0 = *(const float4*)&us[(e0+0)*USS + kk];
    float4 u1 = *(const float4*)&us[(e0+1)*USS + kk];
    float4 u2 = *(const float4*)&us[(e0+2)*USS + kk];
    float4 u3 = *(const float4*)&us[(e0+3)*USS + kk];
    float4 w0 = *(const float4*)&Ws[(jj+0)*WSS + wofs + kk];
    float4 w1 = *(const float4*)&Ws[(jj+1)*WSS + wofs + kk];
    float4 w2 = *(const float4*)&Ws[(jj+2)*WSS + wofs + kk];
    float4 w3 = *(const float4*)&Ws[(jj+3)*WSS + wofs + kk];
    acc[0][0]+=D4(u0,w0); acc[0][1]+=D4(u0,w1); acc[0][2]+=D4(u0,w2); acc[0][3]+=D4(u0,w3);
    acc[1][0]+=D4(u1,w0); acc[1][1]+=D4(u1,w1); acc[1][2]+=D4(u1,w2); acc[1][3]+=D4(u1,w3);
    acc[2][0]+=D4(u2,w0); acc[2][1]+=D4(u2,w1); acc[2][2]+=D4(u2,w2); acc[2][3]+=D4(u2,w3);
    acc[3][0]+=D4(u3,w0); acc[3][1]+=D4(u3,w1); acc[3][2]+=D4(u3,w2); acc[3][3]+=D4(u3,w3);
  }
}

__device__ __forceinline__ void zreduce(float acc[4][4]) {
#pragma unroll
  for (int i = 0; i < 4; ++i)
#pragma unroll
    for (int j = 0; j < 4; ++j) {
      float a = acc[i][j];
      a += __shfl_xor(a, 1); a += __shfl_xor(a, 2); a += __shfl_xor(a, 4);
      a += __shfl_xor(a, 8); a += __shfl_xor(a, 16);
      acc[i][j] = a;
    }
}

__global__ void init_flags(unsigned* flags) {
  if (threadIdx.x < NFLAGS)
    __hip_atomic_store(&flags[threadIdx.x], 0u, __ATOMIC_RELAXED, __HIP_MEMORY_SCOPE_AGENT);
}

__global__ __launch_bounds__(1024) void dnc_coop(
    const float* __restrict__ Xproj, const float* __restrict__ Wx,
    const float* __restrict__ Wh, const float* __restrict__ Wif,
    const float* __restrict__ bif,
    float* __restrict__ Uh, float* __restrict__ Vh,
    unsigned* __restrict__ flags)
{
  const int blk = blockIdx.x, tid = threadIdx.x;
  extern __shared__ float sm[];
  unsigned* FH = flags + FH_OFF;
  unsigned* FV = flags + FV_OFF;
  unsigned* FR = flags + FR_OFF;

  if (blk < 32) {
    // ================= STATE BLOCK (one example) =================
    const int e = blk;
    float* L   = sm + SL_L;   float* Ms  = sm + SL_M;
    float* v   = sm + SL_V;   float* wr  = sm + SL_WR;
    float* fw  = sm + SL_FW;  float* bw  = sm + SL_BW;
    float* cr  = sm + SL_CR;  float* usg = sm + SL_USG;
    float* prc = sm + SL_PRC; float* ww  = sm + SL_WW;
    float* su  = sm + SL_SU;  float* cpx = sm + SL_CPX;
    float* Mn  = sm + SL_MN;  float* swv = sm + SL_SW;
    float* cw  = sm + SL_CW;  int*   rnk = (int*)(sm + SL_RNK);
    float* msc = sm + SL_MSC; float* er_ = sm + SL_ER; float* wv_ = sm + SL_WV;

    for (int i = tid; i < SL_TOT; i += 1024) sm[i] = 0.f;
    __syncthreads();

    for (int t = 0; t < TT; ++t) {
      wait_ge(FV, 128, t+1);   // v(t) published by all col-blocks
      // A: v copy (plain cached loads from fresh per-t region)
      if (tid < IFC) v[tid] = Vh[(size_t)t*VHT + e*480 + tid];
      __syncthreads();
      // B: usage update / write sim / key norms / modes / erase-write prep
      if (tid < 128) {
        float ret = 1.f;
#pragma unroll
        for (int r = 0; r < 4; ++r) { float fr = sig_(v[453+r]); ret *= 1.f - fr*wr[r*128+tid]; }
        float u = usg[tid], w_ = ww[tid];
        usg[tid] = (u + w_ - u*w_) * ret;
      } else if (tid < 256) {
        int n = tid - 128; float nk = 0.f, dot = 0.f;
#pragma unroll
        for (int w = 0; w < 64; w += 4) {
          float4 k4 = *(float4*)&v[260+w];
          float4 m4 = *(float4*)&Ms[n*MST+w];
          nk += D4(k4,k4); dot += D4(m4,k4);
        }
        float beta = 1.f + sp_(v[324]);
        swv[n] = beta * dot / ((Mn[n]+EPSF)*(sqrtf(nk)+EPSF));
      } else if (tid < 260) {
        int r = tid - 256; float s = 0.f;
#pragma unroll
        for (int w = 0; w < 64; w += 4) { float4 k4 = *(float4*)&v[r*64+w]; s += D4(k4,k4); }
        msc[1+r] = sqrtf(s);
      } else if (tid == 260) {
        for (int r = 0; r < 4; ++r) {
          float a0 = v[459+r*3], a1 = v[459+r*3+1], a2 = v[459+r*3+2];
          float mx = fmaxf(a0, fmaxf(a1, a2));
          float e0 = expf(a0-mx), e1 = expf(a1-mx), e2 = expf(a2-mx);
          float dn = e0+e1+e2;
          msc[8+r*3] = e0/dn; msc[8+r*3+1] = e1/dn; msc[8+r*3+2] = e2/dn;
        }
      } else if (tid >= 640 && tid < 704) { int w = tid-640; er_[w] = sig_(v[325+w]); }
      else if (tid >= 704 && tid < 768) { int w = tid-704; wv_[w] = v[389+w]; }
      __syncthreads();
      // C: stable-ascending rank + write softmax
      if (tid < 128) {
        float ui = usg[tid]; int rk = 0;
        for (int j = 0; j < 128; ++j) {
          float uj = usg[j];
          rk += (uj < ui || (uj == ui && j < tid)) ? 1 : 0;
        }
        rnk[tid] = rk; su[rk] = ui;
      } else if (tid < 192) {
        int l = tid - 128;
        float s1 = swv[l], s2 = swv[l+64];
        float m = fmaxf(s1, s2);
#pragma unroll
        for (int o = 32; o > 0; o >>= 1) m = fmaxf(m, __shfl_xor(m, o));
        float e1 = expf(s1-m), e2 = expf(s2-m);
        float dn = e1 + e2;
#pragma unroll
        for (int o = 32; o > 0; o >>= 1) dn += __shfl_xor(dn, o);
        cw[l] = e1/dn; cw[l+64] = e2/dn;
      }
      __syncthreads();
      // D': exclusive cumprod via wave scan + ww (fused)
      if (tid < 64) {
        float a0 = su[2*tid], a1 = su[2*tid+1];
        float p = a0*a1, sc = p;
#pragma unroll
        for (int off = 1; off < 64; off <<= 1) {
          float o = __shfl_up(sc, off);
          if ((int)tid >= off) sc *= o;
        }
        float ex = __shfl_up(sc, 1);
        if (tid == 0) ex = 1.f;
        cpx[2*tid] = ex;
        cpx[2*tid+1] = ex*a0;
        float ag = sig_(v[457]), wg = sig_(v[458]);
#pragma unroll
        for (int q = 0; q < 2; ++q) {
          int n = 2*tid + q;
          float a_i = (1.f - usg[n]) * cpx[rnk[n]];
          ww[n] = wg * (ag*a_i + (1.f-ag)*cw[n]);
        }
      }
      __syncthreads();
      // F: M erase/write + link update (old prec)
      {
        int n = tid >> 3, q = tid & 7;
        float wwn = ww[n];
        int w8 = q*8;
#pragma unroll
        for (int g = 0; g < 2; ++g) {
          int w = w8 + g*4;
          float4 m = *(float4*)&Ms[n*MST+w];
          float4 e4 = *(float4*)&er_[w];
          float4 v4 = *(float4*)&wv_[w];
          m.x = m.x*(1.f - wwn*e4.x) + wwn*v4.x;
          m.y = m.y*(1.f - wwn*e4.y) + wwn*v4.y;
          m.z = m.z*(1.f - wwn*e4.z) + wwn*v4.z;
          m.w = m.w*(1.f - wwn*e4.w) + wwn*v4.w;
          *(float4*)&Ms[n*MST+w] = m;
        }
        int j16 = q*16;
#pragma unroll
        for (int g = 0; g < 4; ++g) {
          int j = j16 + g*4;
          float4 lv = *(float4*)&L[n*LST + j];
          float4 p4 = *(float4*)&prc[j];
          float4 w4 = *(float4*)&ww[j];
          lv.x = (1.f - wwn - w4.x)*lv.x + wwn*p4.x;
          lv.y = (1.f - wwn - w4.y)*lv.y + wwn*p4.y;
          lv.z = (1.f - wwn - w4.z)*lv.z + wwn*p4.z;
          lv.w = (1.f - wwn - w4.w)*lv.w + wwn*p4.w;
          int d = n - j;
          if (d >= 0 && d < 4) ((float*)&lv)[d] = 0.f;
          *(float4*)&L[n*LST + j] = lv;
        }
      }
      __syncthreads();
      // G: sum(ww) + new M norms
      if (tid < 64) {
        float s = ww[tid] + ww[tid+64];
#pragma unroll
        for (int o = 32; o > 0; o >>= 1) s += __shfl_xor(s, o);
        if (tid == 0) msc[0] = s;
      } else if (tid < 192) {
        int n = tid - 64; float s = 0.f;
#pragma unroll
        for (int w = 0; w < 64; w += 4) { float4 m = *(float4*)&Ms[n*MST+w]; s += D4(m,m); }
        Mn[n] = sqrtf(s);
      }
      __syncthreads();
      // H': fw/bw (tid<256) | prec (256..383) | read sims vs new M (>=512)
      if (tid < 256) {
        int half = tid >> 7, t2 = tid & 127;
        int i0 = (t2 >> 2) * 4, sg = t2 & 3;
        float4 av[4] = {{0,0,0,0},{0,0,0,0},{0,0,0,0},{0,0,0,0}};
        if (half == 0) {
#pragma unroll
          for (int m = 0; m < 8; ++m) {
            int j = sg*4 + m*16;
            float4 w0 = *(float4*)&wr[0*128+j];
            float4 w1 = *(float4*)&wr[1*128+j];
            float4 w2 = *(float4*)&wr[2*128+j];
            float4 w3 = *(float4*)&wr[3*128+j];
            float4 l0 = *(float4*)&L[(i0+0)*LST+j];
            float4 l1 = *(float4*)&L[(i0+1)*LST+j];
            float4 l2 = *(float4*)&L[(i0+2)*LST+j];
            float4 l3 = *(float4*)&L[(i0+3)*LST+j];
            av[0].x+=D4(l0,w0); av[0].y+=D4(l1,w0); av[0].z+=D4(l2,w0); av[0].w+=D4(l3,w0);
            av[1].x+=D4(l0,w1); av[1].y+=D4(l1,w1); av[1].z+=D4(l2,w1); av[1].w+=D4(l3,w1);
            av[2].x+=D4(l0,w2); av[2].y+=D4(l1,w2); av[2].z+=D4(l2,w2); av[2].w+=D4(l3,w2);
            av[3].x+=D4(l0,w3); av[3].y+=D4(l1,w3); av[3].z+=D4(l2,w3); av[3].w+=D4(l3,w3);
          }
        } else {
#pragma unroll
          for (int m = 0; m < 32; ++m) {
            int j = sg + m*4;
            float4 lv = *(float4*)&L[j*LST + i0];
            float w0 = wr[j], w1 = wr[128+j], w2 = wr[256+j], w3 = wr[384+j];
            av[0].x+=w0*lv.x; av[0].y+=w0*lv.y; av[0].z+=w0*lv.z; av[0].w+=w0*lv.w;
            av[1].x+=w1*lv.x; av[1].y+=w1*lv.y; av[1].z+=w1*lv.z; av[1].w+=w1*lv.w;
            av[2].x+=w2*lv.x; av[2].y+=w2*lv.y; av[2].z+=w2*lv.z; av[2].w+=w2*lv.w;
            av[3].x+=w3*lv.x; av[3].y+=w3*lv.y; av[3].z+=w3*lv.z; av[3].w+=w3*lv.w;
          }
        }
#pragma unroll
        for (int r = 0; r < 4; ++r) {
          av[r].x += __shfl_xor(av[r].x,1); av[r].x += __shfl_xor(av[r].x,2);
          av[r].y += __shfl_xor(av[r].y,1); av[r].y += __shfl_xor(av[r].y,2);
          av[r].z += __shfl_xor(av[r].z,1); av[r].z += __shfl_xor(av[r].z,2);
          av[r].w += __shfl_xor(av[r].w,1); av[r].w += __shfl_xor(av[r].w,2);
        }
        if (sg == 0) {
          float* dst = half ? bw : fw;
#pragma unroll
          for (int r = 0; r < 4; ++r) {
            dst[r*128 + i0+0] = av[r].x; dst[r*128 + i0+1] = av[r].y;
            dst[r*128 + i0+2] = av[r].z; dst[r*128 + i0+3] = av[r].w;
          }
        }
      } else if (tid < 384) {
        int n = tid - 256;
        prc[n] = (1.f - msc[0])*prc[n] + ww[n];
      } else if (tid >= 512) {
        int r = (tid >> 7) & 3, n = tid & 127;
        float dot = 0.f;
#pragma unroll
        for (int w = 0; w < 64; w += 4) {
          float4 m4 = *(float4*)&Ms[n*MST+w];
          float4 k4 = *(float4*)&v[r*64+w];
          dot += D4(m4,k4);
        }
        float beta = 1.f + sp_(v[256+r]);
        cr[r*128+n] = beta * dot / ((Mn[n]+EPSF)*(msc[1+r]+EPSF));
      }
      __syncthreads();
      // J': per-head read softmax + wr_n (fused)
      if (tid < 256) {
        int r = tid >> 6, l = tid & 63;
        float s1 = cr[r*128+l], s2 = cr[r*128+l+64];
        float m = fmaxf(s1, s2);
#pragma unroll
        for (int o = 32; o > 0; o >>= 1) m = fmaxf(m, __shfl_xor(m, o));
        float e1 = expf(s1-m), e2 = expf(s2-m);
        float dn = e1 + e2;
#pragma unroll
        for (int o = 32; o > 0; o >>= 1) dn += __shfl_xor(dn, o);
        float m0 = msc[8+r*3], m1 = msc[8+r*3+1], m2 = msc[8+r*3+2];
        wr[r*128+l]    = m0*bw[r*128+l]    + m1*(e1/dn) + m2*fw[r*128+l];
        wr[r*128+l+64] = m0*bw[r*128+l+64] + m1*(e2/dn) + m2*fw[r*128+l+64];
      }
      __syncthreads();
      // L: reads_n = wr_n @ M_n, publish to Uh[t]
      if (tid < 512) {
        int r = tid >> 7, t2 = tid & 127;
        int w0 = (t2 >> 3) * 4, ns = t2 & 7;
        float4 a = {0,0,0,0};
#pragma unroll
        for (int m = 0; m < 16; ++m) {
          int n = ns + m*8;
          float4 mr = *(float4*)&Ms[n*MST + w0];
          float wv = wr[r*128 + n];
          a.x += wv*mr.x; a.y += wv*mr.y; a.z += wv*mr.z; a.w += wv*mr.w;
        }
        a.x += __shfl_xor(a.x,1); a.x += __shfl_xor(a.x,2); a.x += __shfl_xor(a.x,4);
        a.y += __shfl_xor(a.y,1); a.y += __shfl_xor(a.y,2); a.y += __shfl_xor(a.y,4);
        a.z += __shfl_xor(a.z,1); a.z += __shfl_xor(a.z,2); a.z += __shfl_xor(a.z,4);
        a.w += __shfl_xor(a.w,1); a.w += __shfl_xor(a.w,2); a.w += __shfl_xor(a.w,4);
        if (ns == 0) {
          int o = r*64 + w0;
          float2 lo = {a.x, a.y}, hi = {a.z, a.w};
          st2(&Uh[(size_t)t*UHT + e*768 + o], lo);
          st2(&Uh[(size_t)t*UHT + e*768 + o + 2], hi);
        }
      }
      arrive(&FR[e]);   // reads(t) published
    }
  } else {
    // ======== COL BLOCK: z-cols {q*512 + cb*4 + d} + 4 iface cols ========
    const int cb = blk - 32;
    float* Ws = sm + CL_WS;
    float* Wi = sm + CL_WI;
    float* us = sm + CL_US;
    float* zh = sm + CL_ZH;
    float* cst= sm + CL_CS;
    float* hl = sm + CL_HL;
    // load weight slices (once)
    for (int i = tid; i < 16*768; i += 1024) {
      int j = i & 15, k = i >> 4;
      int gc = (j >> 2)*512 + cb*4 + (j & 3);
      Ws[j*WSS + k] = (k < 256) ? Wx[(size_t)(512+k)*ZD + gc]
                                : Wh[(size_t)(k-256)*ZD + gc];
    }
    for (int i = tid; i < 4*512; i += 1024) {
      int j = i & 3, k = i >> 2;
      int col = cb*4 + j;
      Wi[j*WIS + k] = (col < IFC) ? Wif[(size_t)k*IFC + col] : 0.f;
    }
    if (tid < 512) {
      int e2 = tid >> 4, j = tid & 15;
      int gc = (j >> 2)*512 + cb*4 + (j & 3);
      zh[tid] = Xproj[((size_t)e2*TT + 0)*ZD + gc];
    }
    if (tid < 128) cst[tid] = 0.f;
    __syncthreads();
    // gates t=0 (h_prev=0, c_prev=0, reads_prev=0 => z = Xproj)
    if (tid < 128) {
      int e2 = tid >> 2, d = tid & 3;
      float zi = zh[e2*16 + d];
      float zg = zh[e2*16 + 8 + d], zo = zh[e2*16 + 12 + d];
      float cn = sig_(zi)*tanhf(zg);              // f*0 dropped
      float hn = sig_(zo)*tanhf(cn);
      cst[tid] = cn; hl[tid] = hn;
    }
    __syncthreads();
    if (tid < 64) {
      int e2 = tid >> 1, p = tid & 1;
      float2 hv = { hl[e2*4 + 2*p], hl[e2*4 + 2*p + 1] };
      st2(&Uh[(size_t)0*UHT + e2*768 + 256 + cb*4 + 2*p], hv);
    }
    arrive(&FH[cb]);   // h(0) published -> FH[cb]=1

    for (int t = 0; t < TT; ++t) {
      const size_t uhb = (size_t)t*UHT;
      wait_ge(FH, 128, t+1);   // h(t) fully published
      // stage h(t) — plain cached float4 loads of fresh per-t region
      for (int i = tid; i < 4096; i += 1024) {
        int e2 = i >> 7, q4 = (i & 127) * 4;
        *(float4*)&us[e2*USS + q4] = *(const float4*)&Uh[uhb + e2*768 + 256 + q4];
      }
      // prefetch Xproj(t+1) into a register — latency hides under v compute
      float xpr = 0.f;
      if (t+1 < TT && tid < 512) {
        int e2 = tid >> 4, j = tid & 15;
        int gc = (j >> 2)*512 + cb*4 + (j & 3);
        xpr = Xproj[((size_t)e2*TT + t+1)*ZD + gc];
      }
      __syncthreads();
      // v slice: 4 cols, K=512
      if (tid < 512) {
        float accI[4] = {0,0,0,0};
        int e2 = tid >> 4, ks = tid & 15;
#pragma unroll
        for (int g = 0; g < 8; ++g) {
          int kk = g*64 + ks*4;
          float4 u4 = *(const float4*)&us[e2*USS + kk];
#pragma unroll
          for (int j = 0; j < 4; ++j) {
            float4 w4 = *(const float4*)&Wi[j*WIS + kk];
            accI[j] += D4(u4,w4);
          }
        }
#pragma unroll
        for (int j = 0; j < 4; ++j) {
          float a = accI[j];
          a += __shfl_xor(a,1); a += __shfl_xor(a,2); a += __shfl_xor(a,4); a += __shfl_xor(a,8);
          accI[j] = a;
        }
        if (ks == 0) {
          int c0 = cb*4;
          float* vrow = Vh + (size_t)t*VHT + e2*480;
          if (c0+1 < IFC) { float2 vv = {bif[c0]+accI[0], bif[c0+1]+accI[1]}; st2(&vrow[c0], vv); }
          else if (c0 < IFC) st1(&vrow[c0], bif[c0]+accI[0]);
          if (c0+3 < IFC) { float2 vv = {bif[c0+2]+accI[2], bif[c0+3]+accI[3]}; st2(&vrow[c0+2], vv); }
          else if (c0+2 < IFC) st1(&vrow[c0+2], bif[c0+2]+accI[2]);
        }
      }
      arrive(&FV[cb]);   // v(t) published
      if (t+1 < TT) {
        // zh(t+1) = Xproj(t+1) + h(t)@Wh — overlaps state's DNC chain
        if (tid < 512) zh[tid] = xpr;
        __syncthreads();
        float acc[4][4] = {};
        zgemm(Ws, us, 256, 4, acc);
        zreduce(acc);
        int tile = tid >> 5, s = tid & 31;
        int e0 = (tile >> 2)*4, jj = (tile & 3)*4;
        if (s == 0) {
#pragma unroll
          for (int i = 0; i < 4; ++i)
#pragma unroll
            for (int j = 0; j < 4; ++j)
              zh[(e0+i)*16 + jj + j] += acc[i][j];
        }
        wait_ge(FR, 32, t+1);   // reads(t) published by all state blocks
        // stage reads(t)
        for (int i = tid; i < 2048; i += 1024) {
          int e2 = i >> 6, q4 = (i & 63) * 4;
          *(float4*)&us[e2*USS + q4] = *(const float4*)&Uh[uhb + e2*768 + q4];
        }
        __syncthreads();
        float acc2[4][4] = {};
        zgemm(Ws, us, 0, 2, acc2);
        zreduce(acc2);
        if (s == 0) {
#pragma unroll
          for (int i = 0; i < 4; ++i)
#pragma unroll
            for (int j = 0; j < 4; ++j)
              zh[(e0+i)*16 + jj + j] += acc2[i][j];
        }
        __syncthreads();
        // gates -> h(t+1), c update (block-local)
        if (tid < 128) {
          int e2 = tid >> 2, d = tid & 3;
          float zi = zh[e2*16 + d], zf = zh[e2*16 + 4 + d];
          float zg = zh[e2*16 + 8 + d], zo = zh[e2*16 + 12 + d];
          float cn = sig_(zf)*cst[tid] + sig_(zi)*tanhf(zg);
          float hn = sig_(zo)*tanhf(cn);
          cst[tid] = cn; hl[tid] = hn;
        }
        __syncthreads();
        if (tid < 64) {
          int e2 = tid >> 1, p = tid & 1;
          float2 hv = { hl[e2*4 + 2*p], hl[e2*4 + 2*p + 1] };
          st2(&Uh[(size_t)(t+1)*UHT + e2*768 + 256 + cb*4 + 2*p], hv);
        }
        arrive(&FH[cb]);   // h(t+1) published
      }
    }
  }
}

extern "C" void kernel_launch(void* const* d_in, const int* in_sizes, int n_in,
                              void* d_out, int out_size, void* d_ws, size_t ws_size,
                              hipStream_t stream) {
  const float* x   = (const float*)d_in[0];
  const float* Wx  = (const float*)d_in[1];
  const float* Wh  = (const float*)d_in[2];
  const float* bl  = (const float*)d_in[3];
  const float* Wif = (const float*)d_in[4];
  const float* bif = (const float*)d_in[5];
  const float* Wo  = (const float*)d_in[6];
  const float* bo  = (const float*)d_in[7];
  float* out = (float*)d_out;

  float* Xp = (float*)d_ws;                         // 4096*2048
  float* Uh = Xp + (size_t)4096*2048;               // 128*UHT
  float* Vh = Uh + (size_t)TT*UHT;                  // 128*VHT
  unsigned* fl = (unsigned*)(Vh + (size_t)TT*VHT);  // NFLAGS

  // 1) Xproj = x @ Wx[:512] + b_lstm
  gemm_bias<<<dim3(2048/64, 4096/64), dim3(256), 0, stream>>>(x, Wx, bl, Xp, 2048, 512);

  // 2) flags
  init_flags<<<dim3(1), dim3(512), 0, stream>>>(fl);

  // 3) cooperative weight-stationary recurrent core (dataflow sync, RMW flags,
  //    low-rate polling)
  const int smem_bytes = CL_TOT * 4;  // 126784
  (void)hipFuncSetAttribute((const void*)dnc_coop, hipFuncAttributeMaxDynamicSharedMemorySize, smem_bytes);
  void* args[] = { (void*)&Xp, (void*)&Wx, (void*)&Wh, (void*)&Wif, (void*)&bif,
                   (void*)&Uh, (void*)&Vh, (void*)&fl };
  (void)hipLaunchCooperativeKernel((void*)dnc_coop, dim3(NBLK), dim3(1024), args,
                                   (unsigned int)smem_bytes, stream);

  // 4) out = [reads,h] @ W_out + b_out  (reads Uh directly, remaps rows)
  gemm_out<<<dim3(512/64, 4096/64), dim3(256), 0, stream>>>(Uh, Wo, bo, out);
}

// Round 10
// 4173.994 us; speedup vs baseline: 1.3577x; 1.3577x over previous
//
#include <hip/hip_runtime.h>
#include <math.h>

#define TT 128
#define ZD 2048
#define IFC 471
#define EPSF 1e-6f
#define MST 68      // M LDS row stride
#define LST 132     // link LDS row stride
#define NBLK 256
#define UHT 24640   // per-t stride of Uh: 32*768 + 64 guard floats
#define VHT 15424   // per-t stride of Vh: 32*480 + 64 guard floats

// per-group flag region: 96 unsigned (6 cache lines)
// [0..27]=FH (col h arrivals) [32..59]=FV (col v arrivals) [64..67]=FR (state reads)
#define FGRP 96
#define NFLAGS 1024

#define D4(a,b) ((a).x*(b).x + (a).y*(b).y + (a).z*(b).z + (a).w*(b).w)

__device__ __forceinline__ float sig_(float x){ return 1.f/(1.f+expf(-x)); }
__device__ __forceinline__ float sp_(float x){ return fmaxf(x,0.f)+log1pf(expf(-fabsf(x))); }

// -------- agent-scope (write-through) publishes: correct on ANY placement --
__device__ __forceinline__ void st1(float* p, float v){
  unsigned u; __builtin_memcpy(&u,&v,4);
  __hip_atomic_store((unsigned*)p, u, __ATOMIC_RELAXED, __HIP_MEMORY_SCOPE_AGENT);
}
__device__ __forceinline__ void st2(float* p, float2 v){
  unsigned long long u; __builtin_memcpy(&u,&v,8);
  __hip_atomic_store((unsigned long long*)p, u, __ATOMIC_RELAXED, __HIP_MEMORY_SCOPE_AGENT);
}

// -------- dataflow sync (round-8 proven mechanics, group-local populations)
__device__ __forceinline__ void arrive(unsigned* f){
  __syncthreads();   // drains vmcnt(0): payload stores at coherent point first
  if (threadIdx.x == 0)
    __hip_atomic_fetch_add(f, 1u, __ATOMIC_RELAXED, __HIP_MEMORY_SCOPE_AGENT);
}
__device__ __forceinline__ void wait_ge(const unsigned* f, int n, unsigned gen){
  if (threadIdx.x < 64){
    for (int i = threadIdx.x; i < n; i += 64){
      if (__hip_atomic_load(&f[i], __ATOMIC_RELAXED, __HIP_MEMORY_SCOPE_AGENT) >= gen) continue;
      int spins = 0; bool done = false;
      while (spins < 64){
        if (__hip_atomic_load(&f[i], __ATOMIC_RELAXED, __HIP_MEMORY_SCOPE_AGENT) >= gen){ done = true; break; }
        __builtin_amdgcn_s_sleep(1); ++spins;
      }
      if (!done){
        while (__hip_atomic_load(&f[i], __ATOMIC_RELAXED, __HIP_MEMORY_SCOPE_AGENT) < gen)
          __builtin_amdgcn_s_sleep(8);
      }
    }
  }
  __syncthreads();
}

__device__ __forceinline__ unsigned bf16rne(float f){
  unsigned u; __builtin_memcpy(&u,&f,4);
  return (u + 0x7fffu + ((u>>16)&1u)) >> 16;
}
__device__ __forceinline__ float bflo(unsigned w){
  unsigned u = w << 16; float f; __builtin_memcpy(&f,&u,4); return f;
}
__device__ __forceinline__ float bfhi(unsigned w){
  unsigned u = w & 0xffff0000u; float f; __builtin_memcpy(&f,&u,4); return f;
}

// ---------------- GEMM #1: C[M,N] = A[M,K] @ B[K,N] + bias[N]
__global__ __launch_bounds__(256) void gemm_bias(
    const float* __restrict__ A, const float* __restrict__ B,
    const float* __restrict__ bias, float* __restrict__ C,
    int Nc, int K)
{
  __shared__ float As[16][68];
  __shared__ float Bs[16][68];
  const int tid = threadIdx.x;
  const int bx = blockIdx.x, by = blockIdx.y;
  const int tx = tid & 15, ty = tid >> 4;
  const int am = tid >> 2, ak = (tid & 3) * 4;
  const int bk = tid >> 4, bn = (tid & 15) * 4;
  float acc[4][4] = {};
  const float* Ap = A + (size_t)(by*64+am)*K + ak;
  const float* Bp = B + (size_t)bk*Nc + bx*64 + bn;
  for (int k0 = 0; k0 < K; k0 += 16) {
    float4 av = *(const float4*)Ap; Ap += 16;
    float4 bv = *(const float4*)Bp; Bp += (size_t)16*Nc;
    As[ak+0][am]=av.x; As[ak+1][am]=av.y; As[ak+2][am]=av.z; As[ak+3][am]=av.w;
    *(float4*)&Bs[bk][bn] = bv;
    __syncthreads();
#pragma unroll
    for (int kk = 0; kk < 16; ++kk) {
      float4 a4 = *(const float4*)&As[kk][ty*4];
      float4 b4 = *(const float4*)&Bs[kk][tx*4];
      acc[0][0]+=a4.x*b4.x; acc[0][1]+=a4.x*b4.y; acc[0][2]+=a4.x*b4.z; acc[0][3]+=a4.x*b4.w;
      acc[1][0]+=a4.y*b4.x; acc[1][1]+=a4.y*b4.y; acc[1][2]+=a4.y*b4.z; acc[1][3]+=a4.y*b4.w;
      acc[2][0]+=a4.z*b4.x; acc[2][1]+=a4.z*b4.y; acc[2][2]+=a4.z*b4.z; acc[2][3]+=a4.z*b4.w;
      acc[3][0]+=a4.w*b4.x; acc[3][1]+=a4.w*b4.y; acc[3][2]+=a4.w*b4.z; acc[3][3]+=a4.w*b4.w;
    }
    __syncthreads();
  }
  float4 bb = *(const float4*)(bias + bx*64 + tx*4);
#pragma unroll
  for (int i = 0; i < 4; ++i) {
    float4 o;
    o.x = acc[i][0]+bb.x; o.y = acc[i][1]+bb.y; o.z = acc[i][2]+bb.z; o.w = acc[i][3]+bb.w;
    *(float4*)(C + (size_t)(by*64+ty*4+i)*Nc + bx*64 + tx*4) = o;
  }
}

// ---------------- GEMM #2 (output): A rows live in Uh[t][e] layout.
__global__ __launch_bounds__(256) void gemm_out(
    const float* __restrict__ A, const float* __restrict__ B,
    const float* __restrict__ bias, float* __restrict__ C)
{
  __shared__ float As[16][68];
  __shared__ float Bs[16][68];
  const int tid = threadIdx.x;
  const int bx = blockIdx.x, by = blockIdx.y;
  const int tx = tid & 15, ty = tid >> 4;
  const int am = tid >> 2, ak = (tid & 3) * 4;
  const int bk = tid >> 4, bn = (tid & 15) * 4;
  float acc[4][4] = {};
  const int arow = by*64 + am;
  const float* Ap = A + (size_t)(arow >> 5)*UHT + (size_t)(arow & 31)*768 + ak;
  const float* Bp = B + (size_t)bk*512 + bx*64 + bn;
  for (int k0 = 0; k0 < 768; k0 += 16) {
    float4 av = *(const float4*)Ap; Ap += 16;
    float4 bv = *(const float4*)Bp; Bp += (size_t)16*512;
    As[ak+0][am]=av.x; As[ak+1][am]=av.y; As[ak+2][am]=av.z; As[ak+3][am]=av.w;
    *(float4*)&Bs[bk][bn] = bv;
    __syncthreads();
#pragma unroll
    for (int kk = 0; kk < 16; ++kk) {
      float4 a4 = *(const float4*)&As[kk][ty*4];
      float4 b4 = *(const float4*)&Bs[kk][tx*4];
      acc[0][0]+=a4.x*b4.x; acc[0][1]+=a4.x*b4.y; acc[0][2]+=a4.x*b4.z; acc[0][3]+=a4.x*b4.w;
      acc[1][0]+=a4.y*b4.x; acc[1][1]+=a4.y*b4.y; acc[1][2]+=a4.y*b4.z; acc[1][3]+=a4.y*b4.w;
      acc[2][0]+=a4.z*b4.x; acc[2][1]+=a4.z*b4.y; acc[2][2]+=a4.z*b4.z; acc[2][3]+=a4.z*b4.w;
      acc[3][0]+=a4.w*b4.x; acc[3][1]+=a4.w*b4.y; acc[3][2]+=a4.w*b4.z; acc[3][3]+=a4.w*b4.w;
    }
    __syncthreads();
  }
  float4 bb = *(const float4*)(bias + bx*64 + tx*4);
#pragma unroll
  for (int i = 0; i < 4; ++i) {
    int row = by*64 + ty*4 + i;
    int crow = (row & 31)*128 + (row >> 5);   // (e,t) -> e*128+t
    float4 o;
    o.x = acc[i][0]+bb.x; o.y = acc[i][1]+bb.y; o.z = acc[i][2]+bb.z; o.w = acc[i][3]+bb.w;
    *(float4*)(C + (size_t)crow*512 + bx*64 + tx*4) = o;
  }
}

// ---------------- state-block LDS layout (floats)
#define SL_L    0
#define SL_M    16896
#define SL_V    25600
#define SL_WR   26080
#define SL_FW   26592
#define SL_BW   27104
#define SL_CR   27616
#define SL_USG  28128
#define SL_PRC  28256
#define SL_WW   28384
#define SL_SU   28512
#define SL_CPX  28640
#define SL_MN   28768
#define SL_SW   28896
#define SL_CW   29024
#define SL_RNK  29152
#define SL_MSC  29280
#define SL_ER   29344
#define SL_WV   29408
#define SL_TOT  29472

// ---------------- col-block LDS layout
// Wzu: uint[76][389]  = 29564 uints (bf16-pair z-weights, stride 389 anti-conflict)
// Wiu: uint[17][261]  = 4437 uints  (bf16-pair iface weights)
// us:  float[4][772]  (reads 0..255, h 256..767)
// zh:  float[4][76] ; cst: float[76]
#define CWI_U  29564
#define CUS_F  34004
#define CZH_F  37092
#define CCS_F  37396
#define CTOT_F 37548   // 150192 B

__global__ void init_flags(unsigned* flags) {
  if (threadIdx.x < NFLAGS)
    __hip_atomic_store(&flags[threadIdx.x], 0u, __ATOMIC_RELAXED, __HIP_MEMORY_SCOPE_AGENT);
}

__global__ __launch_bounds__(1024) void dnc_coop(
    const float* __restrict__ Xproj, const float* __restrict__ Wx,
    const float* __restrict__ Wh, const float* __restrict__ Wif,
    const float* __restrict__ bif,
    float* __restrict__ Uh, float* __restrict__ Vh,
    unsigned* __restrict__ flags)
{
  const int blk = blockIdx.x, tid = threadIdx.x;
  extern __shared__ float sm[];
  const int g = blk & 7;          // group (heuristically = XCD via round-robin)
  const int role = blk >> 3;      // 0..31 within group
  unsigned* FHg = flags + g*FGRP + 0;
  unsigned* FVg = flags + g*FGRP + 32;
  unsigned* FRg = flags + g*FGRP + 64;

  if (role < 4) {
    // ================= STATE BLOCK (example eg) =================
    const int eg = g*4 + role;
    float* L   = sm + SL_L;   float* Ms  = sm + SL_M;
    float* v   = sm + SL_V;   float* wr  = sm + SL_WR;
    float* fw  = sm + SL_FW;  float* bw  = sm + SL_BW;
    float* cr  = sm + SL_CR;  float* usg = sm + SL_USG;
    float* prc = sm + SL_PRC; float* ww  = sm + SL_WW;
    float* su  = sm + SL_SU;  float* cpx = sm + SL_CPX;
    float* Mn  = sm + SL_MN;  float* swv = sm + SL_SW;
    float* cw  = sm + SL_CW;  int*   rnk = (int*)(sm + SL_RNK);
    float* msc = sm + SL_MSC; float* er_ = sm + SL_ER; float* wv_ = sm + SL_WV;

    for (int i = tid; i < SL_TOT; i += 1024) sm[i] = 0.f;
    __syncthreads();

    for (int t = 0; t < TT; ++t) {
      wait_ge(FVg, 28, t+1);   // v(t) from this group's 28 col-blocks
      if (tid < IFC) v[tid] = Vh[(size_t)t*VHT + eg*480 + tid];
      __syncthreads();
      // B
      if (tid < 128) {
        float ret = 1.f;
#pragma unroll
        for (int r = 0; r < 4; ++r) { float fr = sig_(v[453+r]); ret *= 1.f - fr*wr[r*128+tid]; }
        float u = usg[tid], w_ = ww[tid];
        usg[tid] = (u + w_ - u*w_) * ret;
      } else if (tid < 256) {
        int n = tid - 128; float nk = 0.f, dot = 0.f;
#pragma unroll
        for (int w = 0; w < 64; w += 4) {
          float4 k4 = *(float4*)&v[260+w];
          float4 m4 = *(float4*)&Ms[n*MST+w];
          nk += D4(k4,k4); dot += D4(m4,k4);
        }
        float beta = 1.f + sp_(v[324]);
        swv[n] = beta * dot / ((Mn[n]+EPSF)*(sqrtf(nk)+EPSF));
      } else if (tid < 260) {
        int r = tid - 256; float s = 0.f;
#pragma unroll
        for (int w = 0; w < 64; w += 4) { float4 k4 = *(float4*)&v[r*64+w]; s += D4(k4,k4); }
        msc[1+r] = sqrtf(s);
      } else if (tid == 260) {
        for (int r = 0; r < 4; ++r) {
          float a0 = v[459+r*3], a1 = v[459+r*3+1], a2 = v[459+r*3+2];
          float mx = fmaxf(a0, fmaxf(a1, a2));
          float e0 = expf(a0-mx), e1 = expf(a1-mx), e2 = expf(a2-mx);
          float dn = e0+e1+e2;
          msc[8+r*3] = e0/dn; msc[8+r*3+1] = e1/dn; msc[8+r*3+2] = e2/dn;
        }
      } else if (tid >= 640 && tid < 704) { int w = tid-640; er_[w] = sig_(v[325+w]); }
      else if (tid >= 704 && tid < 768) { int w = tid-704; wv_[w] = v[389+w]; }
      __syncthreads();
      // C
      if (tid < 128) {
        float ui = usg[tid]; int rk = 0;
        for (int j = 0; j < 128; ++j) {
          float uj = usg[j];
          rk += (uj < ui || (uj == ui && j < tid)) ? 1 : 0;
        }
        rnk[tid] = rk; su[rk] = ui;
      } else if (tid < 192) {
        int l = tid - 128;
        float s1 = swv[l], s2 = swv[l+64];
        float m = fmaxf(s1, s2);
#pragma unroll
        for (int o = 32; o > 0; o >>= 1) m = fmaxf(m, __shfl_xor(m, o));
        float e1 = expf(s1-m), e2 = expf(s2-m);
        float dn = e1 + e2;
#pragma unroll
        for (int o = 32; o > 0; o >>= 1) dn += __shfl_xor(dn, o);
        cw[l] = e1/dn; cw[l+64] = e2/dn;
      }
      __syncthreads();
      // D' cumprod + ww
      if (tid < 64) {
        float a0 = su[2*tid], a1 = su[2*tid+1];
        float p = a0*a1, sc = p;
#pragma unroll
        for (int off = 1; off < 64; off <<= 1) {
          float o = __shfl_up(sc, off);
          if ((int)tid >= off) sc *= o;
        }
        float ex = __shfl_up(sc, 1);
        if (tid == 0) ex = 1.f;
        cpx[2*tid] = ex;
        cpx[2*tid+1] = ex*a0;
        float ag = sig_(v[457]), wg = sig_(v[458]);
#pragma unroll
        for (int q = 0; q < 2; ++q) {
          int n = 2*tid + q;
          float a_i = (1.f - usg[n]) * cpx[rnk[n]];
          ww[n] = wg * (ag*a_i + (1.f-ag)*cw[n]);
        }
      }
      __syncthreads();
      // F
      {
        int n = tid >> 3, q = tid & 7;
        float wwn = ww[n];
        int w8 = q*8;
#pragma unroll
        for (int gq = 0; gq < 2; ++gq) {
          int w = w8 + gq*4;
          float4 m = *(float4*)&Ms[n*MST+w];
          float4 e4 = *(float4*)&er_[w];
          float4 v4 = *(float4*)&wv_[w];
          m.x = m.x*(1.f - wwn*e4.x) + wwn*v4.x;
          m.y = m.y*(1.f - wwn*e4.y) + wwn*v4.y;
          m.z = m.z*(1.f - wwn*e4.z) + wwn*v4.z;
          m.w = m.w*(1.f - wwn*e4.w) + wwn*v4.w;
          *(float4*)&Ms[n*MST+w] = m;
        }
        int j16 = q*16;
#pragma unroll
        for (int gq = 0; gq < 4; ++gq) {
          int j = j16 + gq*4;
          float4 lv = *(float4*)&L[n*LST + j];
          float4 p4 = *(float4*)&prc[j];
          float4 w4 = *(float4*)&ww[j];
          lv.x = (1.f - wwn - w4.x)*lv.x + wwn*p4.x;
          lv.y = (1.f - wwn - w4.y)*lv.y + wwn*p4.y;
          lv.z = (1.f - wwn - w4.z)*lv.z + wwn*p4.z;
          lv.w = (1.f - wwn - w4.w)*lv.w + wwn*p4.w;
          int d = n - j;
          if (d >= 0 && d < 4) ((float*)&lv)[d] = 0.f;
          *(float4*)&L[n*LST + j] = lv;
        }
      }
      __syncthreads();
      // G
      if (tid < 64) {
        float s = ww[tid] + ww[tid+64];
#pragma unroll
        for (int o = 32; o > 0; o >>= 1) s += __shfl_xor(s, o);
        if (tid == 0) msc[0] = s;
      } else if (tid < 192) {
        int n = tid - 64; float s = 0.f;
#pragma unroll
        for (int w = 0; w < 64; w += 4) { float4 m = *(float4*)&Ms[n*MST+w]; s += D4(m,m); }
        Mn[n] = sqrtf(s);
      }
      __syncthreads();
      // H'
      if (tid < 256) {
        int half = tid >> 7, t2 = tid & 127;
        int i0 = (t2 >> 2) * 4, sg = t2 & 3;
        float4 av[4] = {{0,0,0,0},{0,0,0,0},{0,0,0,0},{0,0,0,0}};
        if (half == 0) {
#pragma unroll
          for (int m = 0; m < 8; ++m) {
            int j = sg*4 + m*16;
            float4 w0 = *(float4*)&wr[0*128+j];
            float4 w1 = *(float4*)&wr[1*128+j];
            float4 w2 = *(float4*)&wr[2*128+j];
            float4 w3 = *(float4*)&wr[3*128+j];
            float4 l0 = *(float4*)&L[(i0+0)*LST+j];
            float4 l1 = *(float4*)&L[(i0+1)*LST+j];
            float4 l2 = *(float4*)&L[(i0+2)*LST+j];
            float4 l3 = *(float4*)&L[(i0+3)*LST+j];
            av[0].x+=D4(l0,w0); av[0].y+=D4(l1,w0); av[0].z+=D4(l2,w0); av[0].w+=D4(l3,w0);
            av[1].x+=D4(l0,w1); av[1].y+=D4(l1,w1); av[1].z+=D4(l2,w1); av[1].w+=D4(l3,w1);
            av[2].x+=D4(l0,w2); av[2].y+=D4(l1,w2); av[2].z+=D4(l2,w2); av[2].w+=D4(l3,w2);
            av[3].x+=D4(l0,w3); av[3].y+=D4(l1,w3); av[3].z+=D4(l2,w3); av[3].w+=D4(l3,w3);
          }
        } else {
#pragma unroll
          for (int m = 0; m < 32; ++m) {
            int j = sg + m*4;
            float4 lv = *(float4*)&L[j*LST + i0];
            float w0 = wr[j], w1 = wr[128+j], w2 = wr[256+j], w3 = wr[384+j];
            av[0].x+=w0*lv.x; av[0].y+=w0*lv.y; av[0].z+=w0*lv.z; av[0].w+=w0*lv.w;
            av[1].x+=w1*lv.x; av[1].y+=w1*lv.y; av[1].z+=w1*lv.z; av[1].w+=w1*lv.w;
            av[2].x+=w2*lv.x; av[2].y+=w2*lv.y; av[2].z+=w2*lv.z; av[2].w+=w2*lv.w;
            av[3].x+=w3*lv.x; av[3].y+=w3*lv.y; av[3].z+=w3*lv.z; av[3].w+=w3*lv.w;
          }
        }
#pragma unroll
        for (int r = 0; r < 4; ++r) {
          av[r].x += __shfl_xor(av[r].x,1); av[r].x += __shfl_xor(av[r].x,2);
          av[r].y += __shfl_xor(av[r].y,1); av[r].y += __shfl_xor(av[r].y,2);
          av[r].z += __shfl_xor(av[r].z,1); av[r].z += __shfl_xor(av[r].z,2);
          av[r].w += __shfl_xor(av[r].w,1); av[r].w += __shfl_xor(av[r].w,2);
        }
        if (sg == 0) {
          float* dst = half ? bw : fw;
#pragma unroll
          for (int r = 0; r < 4; ++r) {
            dst[r*128 + i0+0] = av[r].x; dst[r*128 + i0+1] = av[r].y;
            dst[r*128 + i0+2] = av[r].z; dst[r*128 + i0+3] = av[r].w;
          }
        }
      } else if (tid < 384) {
        int n = tid - 256;
        prc[n] = (1.f - msc[0])*prc[n] + ww[n];
      } else if (tid >= 512) {
        int r = (tid >> 7) & 3, n = tid & 127;
        float dot = 0.f;
#pragma unroll
        for (int w = 0; w < 64; w += 4) {
          float4 m4 = *(float4*)&Ms[n*MST+w];
          float4 k4 = *(float4*)&v[r*64+w];
          dot += D4(m4,k4);
        }
        float beta = 1.f + sp_(v[256+r]);
        cr[r*128+n] = beta * dot / ((Mn[n]+EPSF)*(msc[1+r]+EPSF));
      }
      __syncthreads();
      // J'
      if (tid < 256) {
        int r = tid >> 6, l = tid & 63;
        float s1 = cr[r*128+l], s2 = cr[r*128+l+64];
        float m = fmaxf(s1, s2);
#pragma unroll
        for (int o = 32; o > 0; o >>= 1) m = fmaxf(m, __shfl_xor(m, o));
        float e1 = expf(s1-m), e2 = expf(s2-m);
        float dn = e1 + e2;
#pragma unroll
        for (int o = 32; o > 0; o >>= 1) dn += __shfl_xor(dn, o);
        float m0 = msc[8+r*3], m1 = msc[8+r*3+1], m2 = msc[8+r*3+2];
        wr[r*128+l]    = m0*bw[r*128+l]    + m1*(e1/dn) + m2*fw[r*128+l];
        wr[r*128+l+64] = m0*bw[r*128+l+64] + m1*(e2/dn) + m2*fw[r*128+l+64];
      }
      __syncthreads();
      // L: reads publish
      if (tid < 512) {
        int r = tid >> 7, t2 = tid & 127;
        int w0 = (t2 >> 3) * 4, ns = t2 & 7;
        float4 a = {0,0,0,0};
#pragma unroll
        for (int m = 0; m < 16; ++m) {
          int n = ns + m*8;
          float4 mr = *(float4*)&Ms[n*MST + w0];
          float wv = wr[r*128 + n];
          a.x += wv*mr.x; a.y += wv*mr.y; a.z += wv*mr.z; a.w += wv*mr.w;
        }
        a.x += __shfl_xor(a.x,1); a.x += __shfl_xor(a.x,2); a.x += __shfl_xor(a.x,4);
        a.y += __shfl_xor(a.y,1); a.y += __shfl_xor(a.y,2); a.y += __shfl_xor(a.y,4);
        a.z += __shfl_xor(a.z,1); a.z += __shfl_xor(a.z,2); a.z += __shfl_xor(a.z,4);
        a.w += __shfl_xor(a.w,1); a.w += __shfl_xor(a.w,2); a.w += __shfl_xor(a.w,4);
        if (ns == 0) {
          int o = r*64 + w0;
          float2 lo = {a.x, a.y}, hi = {a.z, a.w};
          st2(&Uh[(size_t)t*UHT + eg*768 + o], lo);
          st2(&Uh[(size_t)t*UHT + eg*768 + o + 2], hi);
        }
      }
      arrive(&FRg[role]);   // reads(t) published
    }
  } else {
    // ======== COL BLOCK c: h-dims [d0,d1) x 4 gate quadrants + v-cols [v0,v1) ====
    const int c = role - 4;                       // 0..27
    const int egB = g*4;                          // group's first example
    const int d0 = (512*c)/28, d1 = (512*(c+1))/28, Dd = d1-d0, NJ = 4*Dd;
    const int v0 = (471*c)/28, v1 = (471*(c+1))/28, JV = v1-v0;
    unsigned* Wzu = (unsigned*)sm;                // [76][389]
    unsigned* Wiu = (unsigned*)sm + CWI_U;        // [17][261]
    float* us  = sm + CUS_F;                      // [4][772]
    float* zh  = sm + CZH_F;                      // [4][76]
    float* cst = sm + CCS_F;                      // [76]

    // ---- one-time: pack weights to bf16 pairs in LDS
    for (int idx = tid; idx < NJ*384; idx += 1024) {
      int j = idx/384, p = idx - j*384, k = 2*p;
      int q = j/Dd, di = j - q*Dd, gc = q*512 + d0 + di;
      float w0 = (k < 256) ? Wx[(size_t)(512+k)*ZD + gc] : Wh[(size_t)(k-256)*ZD + gc];
      float w1 = (k+1 < 256) ? Wx[(size_t)(513+k)*ZD + gc] : Wh[(size_t)(k-255)*ZD + gc];
      Wzu[j*389 + p] = bf16rne(w0) | (bf16rne(w1) << 16);
    }
    for (int idx = tid; idx < JV*256; idx += 1024) {
      int j = idx/256, p = idx - j*256, k = 2*p, gc = v0 + j;
      float w0 = Wif[(size_t)k*IFC + gc];
      float w1 = Wif[(size_t)(k+1)*IFC + gc];
      Wiu[j*261 + p] = bf16rne(w0) | (bf16rne(w1) << 16);
    }
    if (tid < 76) cst[tid] = 0.f;
    // bootstrap z(0) = Xproj(0)
    if (tid < 4*NJ) {
      int e = tid/NJ, j = tid - e*NJ;
      int q = j/Dd, di = j - q*Dd, gc = q*512 + d0 + di;
      zh[e*76 + j] = Xproj[((size_t)(egB+e)*TT + 0)*ZD + gc];
    }
    __syncthreads();
    if (tid < 4*Dd) {
      int e = tid/Dd, di = tid - e*Dd;
      float zi = zh[e*76 + di], zg = zh[e*76 + 2*Dd + di], zo = zh[e*76 + 3*Dd + di];
      float cn = sig_(zi)*tanhf(zg);
      float hn = sig_(zo)*tanhf(cn);
      cst[tid] = cn;
      st1(&Uh[(size_t)0*UHT + (egB + e)*768 + 256 + d0 + di], hn);
    }
    arrive(&FHg[c]);   // h(0) published

    for (int t = 0; t < TT; ++t) {
      wait_ge(FHg, 28, t+1);   // h(t) complete (group-local)
      // stage h(t): fresh per-t region, plain cached float4
      if (tid < 512) {
        int e = tid >> 7, f4 = (tid & 127) * 4;
        *(float4*)&us[e*772 + 256 + f4] =
            *(const float4*)&Uh[(size_t)t*UHT + (egB+e)*768 + 256 + f4];
      }
      // zh(t+1) init from Xproj
      if (t+1 < TT && tid < 4*NJ) {
        int e = tid/NJ, j = tid - e*NJ;
        int q = j/Dd, di = j - q*Dd, gc = q*512 + d0 + di;
        zh[e*76 + j] = Xproj[((size_t)(egB+e)*TT + t+1)*ZD + gc];
      }
      __syncthreads();
      // v-gemm: 4e x JV cols, K=512, 8-way k-split
      if (tid < 544) {
        int g8 = tid >> 3, ks = tid & 7;
        int e = g8/17, j = g8 - e*17;
        if (j < JV) {
          float acc = 0.f;
#pragma unroll 4
          for (int m = 0; m < 32; ++m) {
            int p = m*8 + ks;
            float2 hv = *(const float2*)&us[e*772 + 256 + 2*p];
            unsigned wu = Wiu[j*261 + p];
            acc += hv.x*bflo(wu) + hv.y*bfhi(wu);
          }
          acc += __shfl_xor(acc,1); acc += __shfl_xor(acc,2); acc += __shfl_xor(acc,4);
          if (ks == 0) {
            int col = v0 + j;
            st1(&Vh[(size_t)t*VHT + (egB+e)*480 + col], bif[col] + acc);
          }
        }
      }
      arrive(&FVg[c]);   // v(t) published
      if (t+1 < TT) {
        // zh += h(t) @ Wh-part (K=512) — overlaps state chain
        if (tid < 608) {
          int q2 = tid >> 1, ks = tid & 1;
          int e = q2/76, j = q2 - e*76;
          if (j < NJ) {
            float acc = 0.f;
#pragma unroll 4
            for (int m = 0; m < 128; ++m) {
              int pp = m*2 + ks;
              float2 hv = *(const float2*)&us[e*772 + 256 + 2*pp];
              unsigned wu = Wzu[j*389 + 128 + pp];
              acc += hv.x*bflo(wu) + hv.y*bfhi(wu);
            }
            acc += __shfl_xor(acc,1);
            if (ks == 0) zh[e*76 + j] += acc;
          }
        }
        wait_ge(FRg, 4, t+1);   // reads(t) from the group's 4 state blocks
        if (tid < 256) {
          int e = tid >> 6, f4 = (tid & 63) * 4;
          *(float4*)&us[e*772 + f4] =
              *(const float4*)&Uh[(size_t)t*UHT + (egB+e)*768 + f4];
        }
        __syncthreads();
        // z += reads(t) @ WxR-part (K=256)
        if (tid < 608) {
          int q2 = tid >> 1, ks = tid & 1;
          int e = q2/76, j = q2 - e*76;
          if (j < NJ) {
            float acc = 0.f;
#pragma unroll 4
            for (int m = 0; m < 64; ++m) {
              int pp = m*2 + ks;
              float2 rv = *(const float2*)&us[e*772 + 2*pp];
              unsigned wu = Wzu[j*389 + pp];
              acc += rv.x*bflo(wu) + rv.y*bfhi(wu);
            }
            acc += __shfl_xor(acc,1);
            if (ks == 0) zh[e*76 + j] += acc;
          }
        }
        __syncthreads();
        // gates -> h(t+1), publish
        if (tid < 4*Dd) {
          int e = tid/Dd, di = tid - e*Dd;
          float zi = zh[e*76 + di],      zf = zh[e*76 + Dd + di];
          float zg = zh[e*76 + 2*Dd+di], zo = zh[e*76 + 3*Dd + di];
          float cn = sig_(zf)*cst[tid] + sig_(zi)*tanhf(zg);
          float hn = sig_(zo)*tanhf(cn);
          cst[tid] = cn;
          st1(&Uh[(size_t)(t+1)*UHT + (egB+e)*768 + 256 + d0 + di], hn);
        }
        arrive(&FHg[c]);   // h(t+1) published
      }
    }
  }
}

extern "C" void kernel_launch(void* const* d_in, const int* in_sizes, int n_in,
                              void* d_out, int out_size, void* d_ws, size_t ws_size,
                              hipStream_t stream) {
  const float* x   = (const float*)d_in[0];
  const float* Wx  = (const float*)d_in[1];
  const float* Wh  = (const float*)d_in[2];
  const float* bl  = (const float*)d_in[3];
  const float* Wif = (const float*)d_in[4];
  const float* bif = (const float*)d_in[5];
  const float* Wo  = (const float*)d_in[6];
  const float* bo  = (const float*)d_in[7];
  float* out = (float*)d_out;

  float* Xp = (float*)d_ws;                         // 4096*2048
  float* Uh = Xp + (size_t)4096*2048;               // 128*UHT
  float* Vh = Uh + (size_t)TT*UHT;                  // 128*VHT
  unsigned* fl = (unsigned*)(Vh + (size_t)TT*VHT);  // NFLAGS

  // 1) Xproj = x @ Wx[:512] + b_lstm
  gemm_bias<<<dim3(2048/64, 4096/64), dim3(256), 0, stream>>>(x, Wx, bl, Xp, 2048, 512);

  // 2) flags
  init_flags<<<dim3(1), dim3(NFLAGS), 0, stream>>>(fl);

  // 3) XCD-sharded cooperative core: 8 groups x (4 state + 28 col) blocks
  const int smem_bytes = CTOT_F * 4;  // 150192
  (void)hipFuncSetAttribute((const void*)dnc_coop, hipFuncAttributeMaxDynamicSharedMemorySize, smem_bytes);
  void* args[] = { (void*)&Xp, (void*)&Wx, (void*)&Wh, (void*)&Wif, (void*)&bif,
                   (void*)&Uh, (void*)&Vh, (void*)&fl };
  (void)hipLaunchCooperativeKernel((void*)dnc_coop, dim3(NBLK), dim3(1024), args,
                                   (unsigned int)smem_bytes, stream);

  // 4) out = [reads,h] @ W_out + b_out
  gemm_out<<<dim3(512/64, 4096/64), dim3(256), 0, stream>>>(Uh, Wo, bo, out);
}